// Round 1
// baseline (34.955 us; speedup 1.0000x reference)
//
#include <hip/hip_runtime.h>
#include <hip/hip_bf16.h>

// WordPooling: hidden_states [B,S,H] fp32, segment_ids [B*S] sorted int32,
// output pooled [num_words, H] fp32 (mean over each contiguous word segment;
// empty words -> zeros).
//
// segment_ids is SORTED, so word w owns the contiguous token range
// [lower_bound(w), lower_bound(w+1)). One block per word; binary search is
// wave-uniform and cheap (seg array = 128 KB, L2-resident across all blocks).

__device__ __forceinline__ int lower_bound_i32(const int* __restrict__ a, int n, int val) {
    int lo = 0, hi = n;
    while (lo < hi) {
        int mid = (lo + hi) >> 1;
        if (a[mid] < val) lo = mid + 1;
        else hi = mid;
    }
    return lo;
}

__global__ __launch_bounds__(256)
void word_pool_kernel(const float* __restrict__ hs,
                      const int* __restrict__ seg,
                      float* __restrict__ out,
                      int n_tokens, int H) {
    const int w = blockIdx.x;

    // Uniform across the block: contiguous token range for this word.
    const int start = lower_bound_i32(seg, n_tokens, w);
    const int end   = lower_bound_i32(seg, n_tokens, w + 1);

    // Each thread owns 4 consecutive fp32 columns (H=1024, 256 threads).
    const int h = threadIdx.x * 4;
    if (h >= H) return;

    float4 acc = make_float4(0.f, 0.f, 0.f, 0.f);
    for (int t = start; t < end; ++t) {
        const float4 v = *reinterpret_cast<const float4*>(&hs[(size_t)t * H + h]);
        acc.x += v.x; acc.y += v.y; acc.z += v.z; acc.w += v.w;
    }

    const int cnt = end - start;
    const float inv = (cnt > 0) ? (1.0f / (float)cnt) : 0.0f;
    acc.x *= inv; acc.y *= inv; acc.z *= inv; acc.w *= inv;

    *reinterpret_cast<float4*>(&out[(size_t)w * H + h]) = acc;
}

extern "C" void kernel_launch(void* const* d_in, const int* in_sizes, int n_in,
                              void* d_out, int out_size, void* d_ws, size_t ws_size,
                              hipStream_t stream) {
    const float* hs  = (const float*)d_in[0];   // [B*S, H] flattened
    const int*   seg = (const int*)d_in[1];     // [B*S], sorted
    // d_in[2] is num_segments (scalar on device); derive from sizes instead.
    float* out = (float*)d_out;

    const int n_tokens = in_sizes[1];              // B*S = 32768
    const int H        = in_sizes[0] / n_tokens;   // 1024
    const int n_words  = out_size / H;             // 8192

    dim3 grid(n_words);
    dim3 block(256);
    word_pool_kernel<<<grid, block, 0, stream>>>(hs, seg, out, n_tokens, H);
}